// Round 1
// 166.785 us; speedup vs baseline: 1.0128x; 1.0128x over previous
//
#include <hip/hip_runtime.h>
#include <math.h>

#define BATCH 2
#define SEQ   2048
#define DMODEL 768
#define NHEAD 12
#define HDIM  64

typedef unsigned short u16;
typedef __attribute__((ext_vector_type(8))) short bf16x8;   // 8 bf16 (4 VGPRs)
typedef __attribute__((ext_vector_type(4))) float f32x4;
typedef __attribute__((ext_vector_type(8))) unsigned short us8;
typedef __attribute__((ext_vector_type(4))) unsigned short us4;

__device__ __forceinline__ u16 f2bf(float f) {
    union { float f; unsigned u; } v; v.f = f;
    unsigned u = v.u;
    u += 0x7fff + ((u >> 16) & 1);   // round-to-nearest-even
    return (u16)(u >> 16);
}

// truncating float->bf16 (1 VALU op); used only for P in flash
__device__ __forceinline__ u16 f2bf_trunc(float f) {
    union { float f; unsigned u; } v; v.f = f;
    return (u16)(v.u >> 16);
}

// async 16B global->LDS (wave-uniform LDS base + lane*16)
__device__ __forceinline__ void g2l16(const void* g, void* l) {
    __builtin_amdgcn_global_load_lds(
        (const __attribute__((address_space(1))) unsigned int*)g,
        (__attribute__((address_space(3))) unsigned int*)(unsigned int)(unsigned long long)(uintptr_t)l,
        16, 0, 0);
}

// stage nrows x 32 bf16 (row-major, stride DMODEL) into LDS [row][32].
__device__ __forceinline__ void stage_rows(const u16* g, u16* lds, int nrows,
                                           int tid) {
    const int row = tid >> 2, col = (tid & 3) * 8;
    g2l16(g + (size_t)row * DMODEL + col, lds + tid * 8);
    if (nrows == 128) {
        g2l16(g + (size_t)(row + 64) * DMODEL + col, lds + 2048 + tid * 8);
    } else if (nrows == 96) {
        if (tid < 128)
            g2l16(g + (size_t)(row + 64) * DMODEL + col, lds + 2048 + tid * 8);
    }
}

// ---------------------------------------------------------------------------
// prep (fused): blocks [0,3072): x fp32 -> bf16 (one float4/thread);
//               blocks [3072,5376): weight transpose+convert, 32x32 tiles,
//               Wt[n][k] = W[k][n], 4 weights.
// ---------------------------------------------------------------------------
__global__ __launch_bounds__(256) void prep(const float* __restrict__ x,
                                            const float* __restrict__ w0,
                                            const float* __restrict__ w1,
                                            const float* __restrict__ w2,
                                            const float* __restrict__ w3,
                                            u16* __restrict__ xb,
                                            u16* __restrict__ Wt_all) {
    __shared__ float t[32][33];
    const int bid = blockIdx.x;
    if (bid < 3072) {
        int i = bid * 256 + threadIdx.x;
        float4 v = ((const float4*)x)[i];
        us4 o;
        o.x = f2bf(v.x); o.y = f2bf(v.y); o.z = f2bf(v.z); o.w = f2bf(v.w);
        *(us4*)&xb[(size_t)i * 4] = o;
    } else {
        const int wid = bid - 3072;
        const int z  = wid / 576;
        const int rr = wid % 576;
        const int by = rr / 24, bx = rr % 24;
        const float* W = z == 0 ? w0 : z == 1 ? w1 : z == 2 ? w2 : w3;
        u16* Wt = Wt_all + (size_t)z * DMODEL * DMODEL;

        int tx = threadIdx.x & 31, ty = threadIdx.x >> 5;   // 32 x 8
        int xg = bx * 32 + tx;
        #pragma unroll
        for (int j = 0; j < 32; j += 8)
            t[ty + j][tx] = W[(size_t)(by * 32 + ty + j) * DMODEL + xg];
        __syncthreads();
        int x2 = by * 32 + tx;
        #pragma unroll
        for (int j = 0; j < 32; j += 8)
            Wt[(size_t)(bx * 32 + ty + j) * DMODEL + x2] = f2bf(t[tx][ty + j]);
    }
}

// ---------------------------------------------------------------------------
// Fused QKV projections, 768 EQUAL jobs (3 blocks/CU, zero tail):
//  blocks [0,512): QK, 128(M=x rows) x 96(N) tiles (32 x 16 jobs);
//                  Q (n<768) pre-scaled 0.125, per-head layout.
//  blocks [512,768): V swapped, 96(M=weight rows) x 128(N=x rows) tiles
//                  (8 x 32 jobs) -> Vt[bh][hd][s].
// ---------------------------------------------------------------------------
__global__ __launch_bounds__(256) void gemm_qkv(
    const u16* __restrict__ xb, const u16* __restrict__ WtQK,
    const u16* __restrict__ WtV,
    const float* __restrict__ bq, const float* __restrict__ bk,
    const float* __restrict__ bv,
    u16* __restrict__ QK, u16* __restrict__ Vt) {

    __shared__ __align__(16) u16 As[128 * 32];
    __shared__ __align__(16) u16 Bs[128 * 32];

    const int tid  = threadIdx.x;
    const int lane = tid & 63;
    const int w    = tid >> 6;
    const int quad = lane >> 4, l16 = lane & 15;
    const int wm   = w >> 1, wn = w & 1;
    const int b    = blockIdx.x;

    if (b < 512) {
        const int m0 = (b >> 4) * 128;
        const int n0 = (b & 15) * 96;          // never straddles 768 (768=8*96)
        f32x4 acc[4][3] = {};
        for (int k0 = 0; k0 < DMODEL; k0 += 32) {
            stage_rows(xb   + (size_t)m0 * DMODEL + k0, As, 128, tid);
            stage_rows(WtQK + (size_t)n0 * DMODEL + k0, Bs,  96, tid);
            __syncthreads();
            bf16x8 af[4], bfr[3];
            #pragma unroll
            for (int i = 0; i < 4; ++i)
                af[i] = *(const bf16x8*)&As[(wm * 64 + i * 16 + l16) * 32 + quad * 8];
            #pragma unroll
            for (int j = 0; j < 3; ++j)
                bfr[j] = *(const bf16x8*)&Bs[(wn * 48 + j * 16 + l16) * 32 + quad * 8];
            #pragma unroll
            for (int i = 0; i < 4; ++i)
                #pragma unroll
                for (int j = 0; j < 3; ++j)
                    acc[i][j] = __builtin_amdgcn_mfma_f32_16x16x32_bf16(af[i], bfr[j], acc[i][j], 0, 0, 0);
            __syncthreads();
        }
        const size_t n_elem = (size_t)BATCH * SEQ * DMODEL;
        #pragma unroll
        for (int j = 0; j < 3; ++j) {
            const int n     = n0 + wn * 48 + j * 16 + l16;
            const int which = n / 768;
            const int nn    = n - which * 768;
            const float bias  = (which == 0 ? bq : bk)[nn];
            const float scale = (which == 0) ? 0.125f : 1.0f;
            const int h = nn >> 6, hd = nn & 63;
            u16* outw = QK + (size_t)which * n_elem;
            #pragma unroll
            for (int i = 0; i < 4; ++i) {
                const int mbase = m0 + wm * 64 + i * 16 + quad * 4;
                #pragma unroll
                for (int r = 0; r < 4; ++r) {
                    const int m  = mbase + r;
                    const int b_ = m >> 11, s_ = m & 2047;
                    outw[(size_t)((b_ * NHEAD + h) * SEQ + s_) * HDIM + hd] =
                        f2bf((acc[i][j][r] + bias) * scale);
                }
            }
        }
    } else {
        const int vj = b - 512;
        const int m0 = (vj & 7) * 96;
        const int n0 = (vj >> 3) * 128;
        f32x4 acc[3][4] = {};
        for (int k0 = 0; k0 < DMODEL; k0 += 32) {
            stage_rows(WtV + (size_t)m0 * DMODEL + k0, As,  96, tid);
            stage_rows(xb  + (size_t)n0 * DMODEL + k0, Bs, 128, tid);
            __syncthreads();
            bf16x8 af[3], bfr[4];
            #pragma unroll
            for (int i = 0; i < 3; ++i)
                af[i] = *(const bf16x8*)&As[(wm * 48 + i * 16 + l16) * 32 + quad * 8];
            #pragma unroll
            for (int j = 0; j < 4; ++j)
                bfr[j] = *(const bf16x8*)&Bs[(wn * 64 + j * 16 + l16) * 32 + quad * 8];
            #pragma unroll
            for (int i = 0; i < 3; ++i)
                #pragma unroll
                for (int j = 0; j < 4; ++j)
                    acc[i][j] = __builtin_amdgcn_mfma_f32_16x16x32_bf16(af[i], bfr[j], acc[i][j], 0, 0, 0);
            __syncthreads();
        }
        #pragma unroll
        for (int i = 0; i < 3; ++i) {
            const int rbase = m0 + wm * 48 + i * 16 + quad * 4;
            #pragma unroll
            for (int r = 0; r < 4; ++r) {
                const int row_g = rbase + r;            // 0..767
                const float bias = bv[row_g];
                const int h = row_g >> 6, hd = row_g & 63;
                #pragma unroll
                for (int j = 0; j < 4; ++j) {
                    const int col_g = n0 + wn * 64 + j * 16 + l16;
                    const int b_ = col_g >> 11, s_ = col_g & 2047;
                    Vt[(size_t)((b_ * NHEAD + h) * HDIM + hd) * SEQ + s_] =
                        f2bf(acc[i][j][r] + bias);
                }
            }
        }
    }
}

// ---------------------------------------------------------------------------
// Output projection, 64x64 tiles, grid 768 (3 blocks/CU).
// ---------------------------------------------------------------------------
__global__ __launch_bounds__(256) void gemm_out(
    const u16* __restrict__ Ag, const u16* __restrict__ Bt,
    const float* __restrict__ bo, float* __restrict__ out) {

    __shared__ __align__(16) u16 As[64 * 32];
    __shared__ __align__(16) u16 Bs[64 * 32];

    const int tid  = threadIdx.x;
    const int lane = tid & 63;
    const int w    = tid >> 6;
    const int quad = lane >> 4, l16 = lane & 15;
    const int wm   = w >> 1, wn = w & 1;
    const int m0 = blockIdx.x * 64, n0 = blockIdx.y * 64;

    const int rowA = tid >> 2;            // 0..63
    const int kch  = (tid & 3) * 8;

    f32x4 acc[2][2] = {};

    for (int k0 = 0; k0 < DMODEL; k0 += 32) {
        g2l16(Ag + (size_t)(m0 + rowA) * DMODEL + k0 + kch, As + tid * 8);
        g2l16(Bt + (size_t)(n0 + rowA) * DMODEL + k0 + kch, Bs + tid * 8);
        __syncthreads();

        bf16x8 af[2], bfr[2];
        #pragma unroll
        for (int i = 0; i < 2; ++i)
            af[i] = *(const bf16x8*)&As[(wm * 32 + i * 16 + l16) * 32 + quad * 8];
        #pragma unroll
        for (int j = 0; j < 2; ++j)
            bfr[j] = *(const bf16x8*)&Bs[(wn * 32 + j * 16 + l16) * 32 + quad * 8];
        #pragma unroll
        for (int i = 0; i < 2; ++i)
            #pragma unroll
            for (int j = 0; j < 2; ++j)
                acc[i][j] = __builtin_amdgcn_mfma_f32_16x16x32_bf16(af[i], bfr[j], acc[i][j], 0, 0, 0);
        __syncthreads();
    }

    #pragma unroll
    for (int i = 0; i < 2; ++i) {
        const int mbase = m0 + wm * 32 + i * 16 + quad * 4;
        #pragma unroll
        for (int r = 0; r < 4; ++r) {
            const int m = mbase + r;
            #pragma unroll
            for (int j = 0; j < 2; ++j) {
                const int n = n0 + wn * 32 + j * 16 + l16;
                out[(size_t)m * DMODEL + n] = acc[i][j][r] + bo[n];
            }
        }
    }
}

// ---------------------------------------------------------------------------
// MFMA flash attention v2 — restructured from the anti-diagonal-paired round-9
// kernel based on rocprof evidence (MfmaUtil 11.8%, VALUBusy 31%, HBM 4.7%:
// structure/latency-bound, not roofline-bound):
//  * Block = ONE 64-row q-tile (4 waves x 16 rows). Every wave computes on
//    every staged tile; loop runs exactly tc = j+1 key-tiles. Staged tiles
//    drop 18816 -> 12672 (the old pairing sized the loop for the big tile
//    while the small-tile waves idled ~65% of iterations).
//  * K/V staged via global_load_lds (width 16) into double-buffered LINEAR
//    LDS with an XOR-swizzled per-lane GLOBAL source (rule: linear dest +
//    inverse-swizzled source + same-XOR read). phys_chunk = log_chunk^(row&7)
//    -> ds_read_b128 column-slices are conflict-free; no VGPR round-trip,
//    no ds_write staging, ONE barrier per tile (its implicit vmcnt(0) drain
//    completes the prefetch issued before compute = T3-minimum 2-phase).
//  * Serpentine 3-round blockIdx -> (j,bh) map: CU c's three resident blocks
//    get rounds {asc, desc, asc} of the cost-sorted task list -> per-CU
//    iteration totals ~(1023+c)/24+3 in [46,56] vs [64,80] before.
//  * P bank-swizzled round-trip, streaming-sum softmax (no running max; Q
//    pre-scaled 0.125), truncating P convert, epilogue: unchanged.
//  LDS: 2*8K (K) + 2*8K (V) + 9216 (P) = 41984 B -> 3 blocks/CU.
// ---------------------------------------------------------------------------
__global__ __launch_bounds__(256) void flash_attn_mfma(
    const u16* __restrict__ Q, const u16* __restrict__ K,
    const u16* __restrict__ Vt, u16* __restrict__ A) {

    __shared__ __align__(16) u16 Kl[2][64 * 64];   // [key][d], chunk-swizzled
    __shared__ __align__(16) u16 Vl[2][64 * 64];   // [d][key], chunk-swizzled
    __shared__ __align__(16) u16 Pl[4][16 * 72];   // per-wave P (swizzled)

    const int tid  = threadIdx.x;
    const int lane = tid & 63;
    const int w    = tid >> 6;
    const int quad = lane >> 4;
    const int l16  = lane & 15;

    // serpentine task map (assumes CU gets blockIdx.x = c mod 256)
    const int lin = blockIdx.x;
    const int cc_ = lin & 255, rk = lin >> 8;           // rk = 0..2
    const int sid = (rk << 8) + ((rk & 1) ? (255 - cc_) : cc_);
    const int j   = sid / 24;                           // q-tile 0..31
    const int bh  = sid - j * 24;
    const int tc  = j + 1;                              // key tiles needed

    const size_t base = (size_t)bh * SEQ * HDIM;
    const u16* Qg = Q + base;
    const u16* Kg = K + base;
    const u16* Vg = Vt + base;                          // [hd][s] per head

    const int wrow0 = j * 64 + w * 16;                  // wave's first q row
    const int qrow  = wrow0 + quad * 4;                 // + r = global q row

    bf16x8 qf0 = *(const bf16x8*)&Qg[(size_t)(wrow0 + l16) * 64 + quad * 8];
    bf16x8 qf1 = *(const bf16x8*)&Qg[(size_t)(wrow0 + l16) * 64 + quad * 8 + 32];

    f32x4 o[4] = {};
    float l_acc[4] = {0.f, 0.f, 0.f, 0.f};

    // P-swizzle lane constants (unchanged from round 9)
    const int pwbase = 2 * quad + (l16 >> 3);                  // write chunk base
    const int prd0   = (quad + 2 * (l16 >> 2)) & 7;            // read chunk frag0
    u16* Pw = Pl[w];
    const u16* pr0 = &Pw[l16 * 72 + prd0 * 8];
    const u16* pr1 = &Pw[l16 * 72 + (prd0 ^ 4) * 8];

    // async stage of one 64-key tile into buffer b; 4 g2l16 / thread.
    // LDS chunk ch (16B) of row r holds GLOBAL chunk (ch&7)^(r&7).
    auto STAGE = [&](int t, int b) {
        const int j0 = t * 64;
        #pragma unroll
        for (int h = 0; h < 2; ++h) {
            const int ch = tid + h * 256;              // chunk 0..511
            const int r  = ch >> 3;                    // LDS row
            const int lc = (ch & 7) ^ (r & 7);         // logical chunk
            g2l16(Kg + (size_t)(j0 + r) * 64 + lc * 8, &Kl[b][ch * 8]);
            g2l16(Vg + (size_t)r * SEQ + j0 + lc * 8,  &Vl[b][ch * 8]);
        }
    };

    STAGE(0, 0);
    __syncthreads();          // implicit vmcnt(0) drain completes stage

    int cur = 0;
    for (int t = 0; t < tc; ++t) {
        if (t + 1 < tc) STAGE(t + 1, cur ^ 1);   // prefetch under compute

        const int j0 = t * 64;
        const u16* Kc = Kl[cur];
        const u16* Vc = Vl[cur];

        // ---- QK^T ---- (read swizzle: phys = logical ^ (row&7))
        f32x4 s[4];
        #pragma unroll
        for (int c4 = 0; c4 < 4; ++c4) {
            const int krow = c4 * 16 + l16;
            const int pc = (quad ^ (krow & 7)) * 8;
            bf16x8 kf0 = *(const bf16x8*)&Kc[krow * 64 + pc];
            bf16x8 kf1 = *(const bf16x8*)&Kc[krow * 64 + (pc ^ 32)];
            f32x4 a2 = {};
            a2 = __builtin_amdgcn_mfma_f32_16x16x32_bf16(qf0, kf0, a2, 0, 0, 0);
            a2 = __builtin_amdgcn_mfma_f32_16x16x32_bf16(qf1, kf1, a2, 0, 0, 0);
            s[c4] = a2;
        }

        // ---- causal mask: only the diagonal tile needs it ----
        if (t == tc - 1) {
            #pragma unroll
            for (int c4 = 0; c4 < 4; ++c4) {
                const int jg = j0 + c4 * 16 + l16;
                #pragma unroll
                for (int r = 0; r < 4; ++r)
                    if (jg > qrow + r) s[c4][r] = -INFINITY;
            }
        }

        // ---- streaming exp + per-lane partial denominators ----
        #pragma unroll
        for (int c4 = 0; c4 < 4; ++c4)
            #pragma unroll
            for (int r = 0; r < 4; ++r)
                s[c4][r] = __expf(s[c4][r]);        // masked: exp(-inf)=0
        #pragma unroll
        for (int r = 0; r < 4; ++r)
            l_acc[r] += (s[0][r] + s[1][r]) + (s[2][r] + s[3][r]);

        // ---- P: C-layout -> A-layout via swizzled per-wave LDS round-trip ----
        #pragma unroll
        for (int c4 = 0; c4 < 4; ++c4) {
            const int pc = ((2 * c4 + pwbase) & 7) * 8 + (l16 & 7);
            #pragma unroll
            for (int r = 0; r < 4; ++r)
                Pw[(quad * 4 + r) * 72 + pc] = f2bf_trunc(s[c4][r]);
        }
        bf16x8 pf0 = *(const bf16x8*)pr0;
        bf16x8 pf1 = *(const bf16x8*)pr1;

        // ---- PV ----
        #pragma unroll
        for (int c2 = 0; c2 < 4; ++c2) {
            const int vrow = c2 * 16 + l16;
            const int vc = (quad ^ (vrow & 7)) * 8;
            bf16x8 vf0 = *(const bf16x8*)&Vc[vrow * 64 + vc];
            bf16x8 vf1 = *(const bf16x8*)&Vc[vrow * 64 + (vc ^ 32)];
            o[c2] = __builtin_amdgcn_mfma_f32_16x16x32_bf16(pf0, vf0, o[c2], 0, 0, 0);
            o[c2] = __builtin_amdgcn_mfma_f32_16x16x32_bf16(pf1, vf1, o[c2], 0, 0, 0);
        }

        __syncthreads();    // drains prefetch vmcnt + protects buffer swap
        cur ^= 1;
    }

    // ---- epilogue: reduce denom across the 16 lanes per row ----
    #pragma unroll
    for (int off = 1; off < 16; off <<= 1)
        #pragma unroll
        for (int r = 0; r < 4; ++r)
            l_acc[r] += __shfl_xor(l_acc[r], off);

    const int b = bh / NHEAD, h = bh % NHEAD;
    #pragma unroll
    for (int r = 0; r < 4; ++r) {
        float inv = 1.0f / l_acc[r];
        int sg = qrow + r;
        u16* dst = A + ((size_t)(b * SEQ + sg)) * DMODEL + h * HDIM;
        #pragma unroll
        for (int c2 = 0; c2 < 4; ++c2)
            dst[c2 * 16 + l16] = f2bf(o[c2][r] * inv);
    }
}

// ---------------------------------------------------------------------------
extern "C" void kernel_launch(void* const* d_in, const int* in_sizes, int n_in,
                              void* d_out, int out_size, void* d_ws, size_t ws_size,
                              hipStream_t stream) {
    const float* x  = (const float*)d_in[0];
    // d_in[1] = mask — pure causal, applied analytically; not read.
    const float* wq = (const float*)d_in[2];
    const float* bq = (const float*)d_in[3];
    const float* wk = (const float*)d_in[4];
    const float* bk = (const float*)d_in[5];
    const float* wv = (const float*)d_in[6];
    const float* bv = (const float*)d_in[7];
    const float* wo = (const float*)d_in[8];
    const float* bo = (const float*)d_in[9];
    float* out = (float*)d_out;

    const size_t n_elem = (size_t)BATCH * SEQ * DMODEL;     // 3,145,728
    const size_t w_elem = (size_t)DMODEL * DMODEL;          //   589,824

    u16* xb     = (u16*)d_ws;                // bf16 x, row-major [4096,768]
    u16* Wt_all = xb + n_elem;               // 4 transposed bf16 weights
    u16* Qw     = Wt_all + 4 * w_elem;       // per-head bf16 [bh][s][hd]
    u16* Vtw    = Qw + 2 * n_elem;           // transposed V bf16 [bh][hd][s]
    u16* Aw     = Vtw + n_elem;              // attn out bf16 [4096,768]

    dim3 blk(256);

    prep<<<dim3(3072 + 2304), blk, 0, stream>>>(x, wq, wk, wv, wo, xb, Wt_all);

    gemm_qkv<<<dim3(768), blk, 0, stream>>>(xb, Wt_all, Wt_all + 2 * w_elem,
                                            bq, bk, bv, Qw, Vtw);

    flash_attn_mfma<<<dim3(768), blk, 0, stream>>>(Qw, Qw + n_elem, Vtw, Aw);

    gemm_out<<<dim3(64, 12), blk, 0, stream>>>(Aw, Wt_all + 3 * w_elem, bo, out);
}

// Round 2
// 162.307 us; speedup vs baseline: 1.0408x; 1.0276x over previous
//
#include <hip/hip_runtime.h>
#include <math.h>

#define BATCH 2
#define SEQ   2048
#define DMODEL 768
#define NHEAD 12
#define HDIM  64

typedef unsigned short u16;
typedef __attribute__((ext_vector_type(8))) short bf16x8;   // 8 bf16 (4 VGPRs)
typedef __attribute__((ext_vector_type(4))) float f32x4;
typedef __attribute__((ext_vector_type(8))) unsigned short us8;
typedef __attribute__((ext_vector_type(4))) unsigned short us4;

__device__ __forceinline__ u16 f2bf(float f) {
    union { float f; unsigned u; } v; v.f = f;
    unsigned u = v.u;
    u += 0x7fff + ((u >> 16) & 1);   // round-to-nearest-even
    return (u16)(u >> 16);
}

// truncating float->bf16 (1 VALU op); used only for P in flash
__device__ __forceinline__ u16 f2bf_trunc(float f) {
    union { float f; unsigned u; } v; v.f = f;
    return (u16)(v.u >> 16);
}

// hardware exp2 (v_exp_f32). Input is pre-scaled by log2(e) upstream.
__device__ __forceinline__ float fexp2(float x) {
#if __has_builtin(__builtin_amdgcn_exp2f)
    return __builtin_amdgcn_exp2f(x);
#else
    return exp2f(x);
#endif
}

// async 16B global->LDS (wave-uniform LDS base + lane*16)
__device__ __forceinline__ void g2l16(const void* g, void* l) {
    __builtin_amdgcn_global_load_lds(
        (const __attribute__((address_space(1))) unsigned int*)g,
        (__attribute__((address_space(3))) unsigned int*)(unsigned int)(unsigned long long)(uintptr_t)l,
        16, 0, 0);
}

// stage nrows x 32 bf16 (row-major, stride DMODEL) into LDS [row][32].
__device__ __forceinline__ void stage_rows(const u16* g, u16* lds, int nrows,
                                           int tid) {
    const int row = tid >> 2, col = (tid & 3) * 8;
    g2l16(g + (size_t)row * DMODEL + col, lds + tid * 8);
    if (nrows == 128) {
        g2l16(g + (size_t)(row + 64) * DMODEL + col, lds + 2048 + tid * 8);
    } else if (nrows == 96) {
        if (tid < 128)
            g2l16(g + (size_t)(row + 64) * DMODEL + col, lds + 2048 + tid * 8);
    }
}

// ---------------------------------------------------------------------------
// prep (fused): blocks [0,3072): x fp32 -> bf16 (one float4/thread);
//               blocks [3072,5376): weight transpose+convert, 32x32 tiles,
//               Wt[n][k] = W[k][n], 4 weights.
// ---------------------------------------------------------------------------
__global__ __launch_bounds__(256) void prep(const float* __restrict__ x,
                                            const float* __restrict__ w0,
                                            const float* __restrict__ w1,
                                            const float* __restrict__ w2,
                                            const float* __restrict__ w3,
                                            u16* __restrict__ xb,
                                            u16* __restrict__ Wt_all) {
    __shared__ float t[32][33];
    const int bid = blockIdx.x;
    if (bid < 3072) {
        int i = bid * 256 + threadIdx.x;
        float4 v = ((const float4*)x)[i];
        us4 o;
        o.x = f2bf(v.x); o.y = f2bf(v.y); o.z = f2bf(v.z); o.w = f2bf(v.w);
        *(us4*)&xb[(size_t)i * 4] = o;
    } else {
        const int wid = bid - 3072;
        const int z  = wid / 576;
        const int rr = wid % 576;
        const int by = rr / 24, bx = rr % 24;
        const float* W = z == 0 ? w0 : z == 1 ? w1 : z == 2 ? w2 : w3;
        u16* Wt = Wt_all + (size_t)z * DMODEL * DMODEL;

        int tx = threadIdx.x & 31, ty = threadIdx.x >> 5;   // 32 x 8
        int xg = bx * 32 + tx;
        #pragma unroll
        for (int j = 0; j < 32; j += 8)
            t[ty + j][tx] = W[(size_t)(by * 32 + ty + j) * DMODEL + xg];
        __syncthreads();
        int x2 = by * 32 + tx;
        #pragma unroll
        for (int j = 0; j < 32; j += 8)
            Wt[(size_t)(bx * 32 + ty + j) * DMODEL + x2] = f2bf(t[tx][ty + j]);
    }
}

// ---------------------------------------------------------------------------
// Fused QKV projections, 768 EQUAL jobs (3 blocks/CU, zero tail):
//  blocks [0,512): QK, 128(M=x rows) x 96(N) tiles (32 x 16 jobs);
//                  Q (n<768) pre-scaled 0.125*log2(e) (flash uses exp2),
//                  per-head layout.
//  blocks [512,768): V swapped, 96(M=weight rows) x 128(N=x rows) tiles
//                  (8 x 32 jobs) -> Vt[bh][hd][s].
// ---------------------------------------------------------------------------
__global__ __launch_bounds__(256) void gemm_qkv(
    const u16* __restrict__ xb, const u16* __restrict__ WtQK,
    const u16* __restrict__ WtV,
    const float* __restrict__ bq, const float* __restrict__ bk,
    const float* __restrict__ bv,
    u16* __restrict__ QK, u16* __restrict__ Vt) {

    __shared__ __align__(16) u16 As[128 * 32];
    __shared__ __align__(16) u16 Bs[128 * 32];

    const int tid  = threadIdx.x;
    const int lane = tid & 63;
    const int w    = tid >> 6;
    const int quad = lane >> 4, l16 = lane & 15;
    const int wm   = w >> 1, wn = w & 1;
    const int b    = blockIdx.x;

    if (b < 512) {
        const int m0 = (b >> 4) * 128;
        const int n0 = (b & 15) * 96;          // never straddles 768 (768=8*96)
        f32x4 acc[4][3] = {};
        for (int k0 = 0; k0 < DMODEL; k0 += 32) {
            stage_rows(xb   + (size_t)m0 * DMODEL + k0, As, 128, tid);
            stage_rows(WtQK + (size_t)n0 * DMODEL + k0, Bs,  96, tid);
            __syncthreads();
            bf16x8 af[4], bfr[3];
            #pragma unroll
            for (int i = 0; i < 4; ++i)
                af[i] = *(const bf16x8*)&As[(wm * 64 + i * 16 + l16) * 32 + quad * 8];
            #pragma unroll
            for (int j = 0; j < 3; ++j)
                bfr[j] = *(const bf16x8*)&Bs[(wn * 48 + j * 16 + l16) * 32 + quad * 8];
            #pragma unroll
            for (int i = 0; i < 4; ++i)
                #pragma unroll
                for (int j = 0; j < 3; ++j)
                    acc[i][j] = __builtin_amdgcn_mfma_f32_16x16x32_bf16(af[i], bfr[j], acc[i][j], 0, 0, 0);
            __syncthreads();
        }
        const size_t n_elem = (size_t)BATCH * SEQ * DMODEL;
        #pragma unroll
        for (int j = 0; j < 3; ++j) {
            const int n     = n0 + wn * 48 + j * 16 + l16;
            const int which = n / 768;
            const int nn    = n - which * 768;
            const float bias  = (which == 0 ? bq : bk)[nn];
            // Q pre-scale folds softmax 1/sqrt(HD) AND log2(e) for exp2 path
            const float scale = (which == 0) ? 0.18033688011112043f : 1.0f;
            const int h = nn >> 6, hd = nn & 63;
            u16* outw = QK + (size_t)which * n_elem;
            #pragma unroll
            for (int i = 0; i < 4; ++i) {
                const int mbase = m0 + wm * 64 + i * 16 + quad * 4;
                #pragma unroll
                for (int r = 0; r < 4; ++r) {
                    const int m  = mbase + r;
                    const int b_ = m >> 11, s_ = m & 2047;
                    outw[(size_t)((b_ * NHEAD + h) * SEQ + s_) * HDIM + hd] =
                        f2bf((acc[i][j][r] + bias) * scale);
                }
            }
        }
    } else {
        const int vj = b - 512;
        const int m0 = (vj & 7) * 96;
        const int n0 = (vj >> 3) * 128;
        f32x4 acc[3][4] = {};
        for (int k0 = 0; k0 < DMODEL; k0 += 32) {
            stage_rows(WtV + (size_t)m0 * DMODEL + k0, As,  96, tid);
            stage_rows(xb  + (size_t)n0 * DMODEL + k0, Bs, 128, tid);
            __syncthreads();
            bf16x8 af[3], bfr[4];
            #pragma unroll
            for (int i = 0; i < 3; ++i)
                af[i] = *(const bf16x8*)&As[(wm * 48 + i * 16 + l16) * 32 + quad * 8];
            #pragma unroll
            for (int j = 0; j < 4; ++j)
                bfr[j] = *(const bf16x8*)&Bs[(wn * 64 + j * 16 + l16) * 32 + quad * 8];
            #pragma unroll
            for (int i = 0; i < 3; ++i)
                #pragma unroll
                for (int j = 0; j < 4; ++j)
                    acc[i][j] = __builtin_amdgcn_mfma_f32_16x16x32_bf16(af[i], bfr[j], acc[i][j], 0, 0, 0);
            __syncthreads();
        }
        #pragma unroll
        for (int i = 0; i < 3; ++i) {
            const int rbase = m0 + wm * 48 + i * 16 + quad * 4;
            #pragma unroll
            for (int r = 0; r < 4; ++r) {
                const int row_g = rbase + r;            // 0..767
                const float bias = bv[row_g];
                const int h = row_g >> 6, hd = row_g & 63;
                #pragma unroll
                for (int j = 0; j < 4; ++j) {
                    const int col_g = n0 + wn * 64 + j * 16 + l16;
                    const int b_ = col_g >> 11, s_ = col_g & 2047;
                    Vt[(size_t)((b_ * NHEAD + h) * HDIM + hd) * SEQ + s_] =
                        f2bf(acc[i][j][r] + bias);
                }
            }
        }
    }
}

// ---------------------------------------------------------------------------
// Output projection, 64x64 tiles, grid 768 (3 blocks/CU).
// ---------------------------------------------------------------------------
__global__ __launch_bounds__(256) void gemm_out(
    const u16* __restrict__ Ag, const u16* __restrict__ Bt,
    const float* __restrict__ bo, float* __restrict__ out) {

    __shared__ __align__(16) u16 As[64 * 32];
    __shared__ __align__(16) u16 Bs[64 * 32];

    const int tid  = threadIdx.x;
    const int lane = tid & 63;
    const int w    = tid >> 6;
    const int quad = lane >> 4, l16 = lane & 15;
    const int wm   = w >> 1, wn = w & 1;
    const int m0 = blockIdx.x * 64, n0 = blockIdx.y * 64;

    const int rowA = tid >> 2;            // 0..63
    const int kch  = (tid & 3) * 8;

    f32x4 acc[2][2] = {};

    for (int k0 = 0; k0 < DMODEL; k0 += 32) {
        g2l16(Ag + (size_t)(m0 + rowA) * DMODEL + k0 + kch, As + tid * 8);
        g2l16(Bt + (size_t)(n0 + rowA) * DMODEL + k0 + kch, Bs + tid * 8);
        __syncthreads();

        bf16x8 af[2], bfr[2];
        #pragma unroll
        for (int i = 0; i < 2; ++i)
            af[i] = *(const bf16x8*)&As[(wm * 32 + i * 16 + l16) * 32 + quad * 8];
        #pragma unroll
        for (int j = 0; j < 2; ++j)
            bfr[j] = *(const bf16x8*)&Bs[(wn * 32 + j * 16 + l16) * 32 + quad * 8];
        #pragma unroll
        for (int i = 0; i < 2; ++i)
            #pragma unroll
            for (int j = 0; j < 2; ++j)
                acc[i][j] = __builtin_amdgcn_mfma_f32_16x16x32_bf16(af[i], bfr[j], acc[i][j], 0, 0, 0);
        __syncthreads();
    }

    #pragma unroll
    for (int i = 0; i < 2; ++i) {
        const int mbase = m0 + wm * 32 + i * 16 + quad * 4;
        #pragma unroll
        for (int r = 0; r < 4; ++r) {
            const int m = mbase + r;
            #pragma unroll
            for (int j = 0; j < 2; ++j) {
                const int n = n0 + wn * 32 + j * 16 + l16;
                out[(size_t)m * DMODEL + n] = acc[i][j][r] + bo[n];
            }
        }
    }
}

// ---------------------------------------------------------------------------
// MFMA flash attention v3 — v2's per-iteration latency chain (inferred
// ~1.25us/iter vs ~80cy MFMA payload) attacked with:
//  * RING-3 K/V buffers + DEPTH-2 prefetch + counted vmcnt(4) (T4): iteration
//    t waits only for STAGE(t) (issued 2 iterations earlier — latency fully
//    hidden even from L3/HBM), leaves STAGE(t+1) in flight, raw s_barrier,
//    then issues STAGE(t+2). Never drains vmcnt to 0 mid-loop.
//    Race-free with ONE barrier/iter: STAGE(t+2) writes buf (t+2)%3 =
//    (t-1)%3, whose iter-(t-1) readers all passed the iter-t barrier.
//  * LPT dispatch order (longest q-tiles first): LDS 58368B -> 2 blocks/CU;
//    the 256 blocks that queue behind the 512 resident are the tc<=11 stubs.
//  * exp2 path: Q pre-scaled by 0.125*log2(e) upstream; softmax uses raw
//    v_exp_f32 (16 fewer v_mul per iter per wave on the critical chain).
//  * s_setprio(1) around QK/PV MFMA clusters (T5, attn-proven +4-7%).
//  * K/V chunk-XOR swizzle via pre-swizzled global source (unchanged);
//    P bank-swizzled round-trip, streaming-sum softmax (no running max),
//    truncating P convert, epilogue: unchanged.
// ---------------------------------------------------------------------------
__global__ __launch_bounds__(256) void flash_attn_mfma(
    const u16* __restrict__ Q, const u16* __restrict__ K,
    const u16* __restrict__ Vt, u16* __restrict__ A) {

    __shared__ __align__(16) u16 Kl[3][64 * 64];   // [key][d], chunk-swizzled
    __shared__ __align__(16) u16 Vl[3][64 * 64];   // [d][key], chunk-swizzled
    __shared__ __align__(16) u16 Pl[4][16 * 72];   // per-wave P (swizzled)

    const int tid  = threadIdx.x;
    const int lane = tid & 63;
    const int w    = tid >> 6;
    const int quad = lane >> 4;
    const int l16  = lane & 15;

    // LPT map: longest tasks (large j) get the smallest blockIdx -> dispatched
    // first; the 256 non-resident stubs at the end are tc<=11.
    const int sid = 767 - (int)blockIdx.x;
    const int j   = sid / 24;                           // q-tile 0..31
    const int bh  = sid - j * 24;
    const int tc  = j + 1;                              // key tiles needed

    const size_t base = (size_t)bh * SEQ * HDIM;
    const u16* Qg = Q + base;
    const u16* Kg = K + base;
    const u16* Vg = Vt + base;                          // [hd][s] per head

    const int wrow0 = j * 64 + w * 16;                  // wave's first q row
    const int qrow  = wrow0 + quad * 4;                 // + r = global q row

    bf16x8 qf0 = *(const bf16x8*)&Qg[(size_t)(wrow0 + l16) * 64 + quad * 8];
    bf16x8 qf1 = *(const bf16x8*)&Qg[(size_t)(wrow0 + l16) * 64 + quad * 8 + 32];

    f32x4 o[4] = {};
    float l_acc[4] = {0.f, 0.f, 0.f, 0.f};

    // P-swizzle lane constants
    const int pwbase = 2 * quad + (l16 >> 3);                  // write chunk base
    const int prd0   = (quad + 2 * (l16 >> 2)) & 7;            // read chunk frag0
    u16* Pw = Pl[w];
    const u16* pr0 = &Pw[l16 * 72 + prd0 * 8];
    const u16* pr1 = &Pw[l16 * 72 + (prd0 ^ 4) * 8];

    // incremental per-thread staging addresses (2 chunks each of K and V).
    // LDS chunk ch (16B) of row r holds GLOBAL chunk (ch&7)^(r&7).
    const int ch0 = tid, ch1 = tid + 256;
    const int r0 = ch0 >> 3, lc0 = (ch0 & 7) ^ (r0 & 7);
    const int r1 = ch1 >> 3, lc1 = (ch1 & 7) ^ (r1 & 7);
    const u16* kp0 = Kg + (size_t)r0 * 64 + lc0 * 8;
    const u16* kp1 = Kg + (size_t)r1 * 64 + lc1 * 8;
    const u16* vp0 = Vg + (size_t)r0 * SEQ + lc0 * 8;
    const u16* vp1 = Vg + (size_t)r1 * SEQ + lc1 * 8;

    auto STAGE = [&](int buf) {
        g2l16(kp0, &Kl[buf][ch0 * 8]);
        g2l16(kp1, &Kl[buf][ch1 * 8]);
        g2l16(vp0, &Vl[buf][ch0 * 8]);
        g2l16(vp1, &Vl[buf][ch1 * 8]);
        kp0 += 64 * 64; kp1 += 64 * 64;   // next 64-key tile (row-major keys)
        vp0 += 64;      vp1 += 64;        // keys contiguous in Vt
    };

    // depth-2 prologue
    STAGE(0);
    if (tc > 1) STAGE(1);

    int cur = 0, nb = 2;
    for (int t = 0; t < tc; ++t) {
        // wait for STAGE(t) only; leave STAGE(t+1) in flight (T4)
        if (t + 1 < tc) asm volatile("s_waitcnt vmcnt(4)" ::: "memory");
        else            asm volatile("s_waitcnt vmcnt(0)" ::: "memory");
        __builtin_amdgcn_s_barrier();
        if (t + 2 < tc) { STAGE(nb); nb = (nb == 2) ? 0 : nb + 1; }

        const int j0 = t * 64;
        const u16* Kc = Kl[cur];
        const u16* Vc = Vl[cur];

        // ---- QK^T ---- (read swizzle: phys = logical ^ (row&7))
        f32x4 s[4];
        __builtin_amdgcn_s_setprio(1);
        #pragma unroll
        for (int c4 = 0; c4 < 4; ++c4) {
            const int krow = c4 * 16 + l16;
            const int pc = (quad ^ (krow & 7)) * 8;
            bf16x8 kf0 = *(const bf16x8*)&Kc[krow * 64 + pc];
            bf16x8 kf1 = *(const bf16x8*)&Kc[krow * 64 + (pc ^ 32)];
            f32x4 a2 = {};
            a2 = __builtin_amdgcn_mfma_f32_16x16x32_bf16(qf0, kf0, a2, 0, 0, 0);
            a2 = __builtin_amdgcn_mfma_f32_16x16x32_bf16(qf1, kf1, a2, 0, 0, 0);
            s[c4] = a2;
        }
        __builtin_amdgcn_s_setprio(0);

        // ---- causal mask: only the diagonal tile needs it ----
        if (t == tc - 1) {
            #pragma unroll
            for (int c4 = 0; c4 < 4; ++c4) {
                const int jg = j0 + c4 * 16 + l16;
                #pragma unroll
                for (int r = 0; r < 4; ++r)
                    if (jg > qrow + r) s[c4][r] = -INFINITY;
            }
        }

        // ---- streaming exp2 + per-lane partial denominators ----
        // (scores were pre-scaled by log2(e) in the Q projection)
        #pragma unroll
        for (int c4 = 0; c4 < 4; ++c4)
            #pragma unroll
            for (int r = 0; r < 4; ++r)
                s[c4][r] = fexp2(s[c4][r]);        // masked: exp2(-inf)=0
        #pragma unroll
        for (int r = 0; r < 4; ++r)
            l_acc[r] += (s[0][r] + s[1][r]) + (s[2][r] + s[3][r]);

        // ---- P: C-layout -> A-layout via swizzled per-wave LDS round-trip ----
        #pragma unroll
        for (int c4 = 0; c4 < 4; ++c4) {
            const int pc = ((2 * c4 + pwbase) & 7) * 8 + (l16 & 7);
            #pragma unroll
            for (int r = 0; r < 4; ++r)
                Pw[(quad * 4 + r) * 72 + pc] = f2bf_trunc(s[c4][r]);
        }
        bf16x8 pf0 = *(const bf16x8*)pr0;
        bf16x8 pf1 = *(const bf16x8*)pr1;

        // ---- PV ----
        __builtin_amdgcn_s_setprio(1);
        #pragma unroll
        for (int c2 = 0; c2 < 4; ++c2) {
            const int vrow = c2 * 16 + l16;
            const int vc = (quad ^ (vrow & 7)) * 8;
            bf16x8 vf0 = *(const bf16x8*)&Vc[vrow * 64 + vc];
            bf16x8 vf1 = *(const bf16x8*)&Vc[vrow * 64 + (vc ^ 32)];
            o[c2] = __builtin_amdgcn_mfma_f32_16x16x32_bf16(pf0, vf0, o[c2], 0, 0, 0);
            o[c2] = __builtin_amdgcn_mfma_f32_16x16x32_bf16(pf1, vf1, o[c2], 0, 0, 0);
        }
        __builtin_amdgcn_s_setprio(0);

        cur = (cur == 2) ? 0 : cur + 1;
    }

    // ---- epilogue: reduce denom across the 16 lanes per row ----
    #pragma unroll
    for (int off = 1; off < 16; off <<= 1)
        #pragma unroll
        for (int r = 0; r < 4; ++r)
            l_acc[r] += __shfl_xor(l_acc[r], off);

    const int b = bh / NHEAD, h = bh % NHEAD;
    #pragma unroll
    for (int r = 0; r < 4; ++r) {
        float inv = 1.0f / l_acc[r];
        int sg = qrow + r;
        u16* dst = A + ((size_t)(b * SEQ + sg)) * DMODEL + h * HDIM;
        #pragma unroll
        for (int c2 = 0; c2 < 4; ++c2)
            dst[c2 * 16 + l16] = f2bf(o[c2][r] * inv);
    }
}

// ---------------------------------------------------------------------------
extern "C" void kernel_launch(void* const* d_in, const int* in_sizes, int n_in,
                              void* d_out, int out_size, void* d_ws, size_t ws_size,
                              hipStream_t stream) {
    const float* x  = (const float*)d_in[0];
    // d_in[1] = mask — pure causal, applied analytically; not read.
    const float* wq = (const float*)d_in[2];
    const float* bq = (const float*)d_in[3];
    const float* wk = (const float*)d_in[4];
    const float* bk = (const float*)d_in[5];
    const float* wv = (const float*)d_in[6];
    const float* bv = (const float*)d_in[7];
    const float* wo = (const float*)d_in[8];
    const float* bo = (const float*)d_in[9];
    float* out = (float*)d_out;

    const size_t n_elem = (size_t)BATCH * SEQ * DMODEL;     // 3,145,728
    const size_t w_elem = (size_t)DMODEL * DMODEL;          //   589,824

    u16* xb     = (u16*)d_ws;                // bf16 x, row-major [4096,768]
    u16* Wt_all = xb + n_elem;               // 4 transposed bf16 weights
    u16* Qw     = Wt_all + 4 * w_elem;       // per-head bf16 [bh][s][hd]
    u16* Vtw    = Qw + 2 * n_elem;           // transposed V bf16 [bh][hd][s]
    u16* Aw     = Vtw + n_elem;              // attn out bf16 [4096,768]

    dim3 blk(256);

    prep<<<dim3(3072 + 2304), blk, 0, stream>>>(x, wq, wk, wv, wo, xb, Wt_all);

    gemm_qkv<<<dim3(768), blk, 0, stream>>>(xb, Wt_all, Wt_all + 2 * w_elem,
                                            bq, bk, bv, Qw, Vtw);

    flash_attn_mfma<<<dim3(768), blk, 0, stream>>>(Qw, Qw + n_elem, Vtw, Aw);

    gemm_out<<<dim3(64, 12), blk, 0, stream>>>(Aw, Wt_all + 3 * w_elem, bo, out);
}